// Round 3
// baseline (317.293 us; speedup 1.0000x reference)
//
#include <hip/hip_runtime.h>
#include <hip/hip_bf16.h>

constexpr int B = 4, N = 8192, S = 2048;
constexpr int LD = 384;   // row stride (elements) of the fused feat/y buffer

typedef __attribute__((ext_vector_type(8))) short short8;
typedef __attribute__((ext_vector_type(4))) float v4f;

__device__ inline float bf2f(__hip_bfloat16 x) { return __bfloat162float(x); }

// ------------------------------------------------------------- zeroing ----
__global__ void zero_k(float* __restrict__ p)
{
    p[blockIdx.x * 256 + threadIdx.x] = 0.f;
}

// ------------------------------------------------------------ cast W -----
__global__ void cast_w(const float* __restrict__ in, __hip_bfloat16* __restrict__ out,
                       int n)
{
    int i = blockIdx.x * 256 + threadIdx.x;
    if (i < n) out[i] = __float2bfloat16(in[i]);
}

// ---------------------------------------------------------------- 3-NN ----
__global__ __launch_bounds__(256) void knn_kernel(
    const float* __restrict__ pos1,
    const float* __restrict__ pos2,
    float* __restrict__ wgt, int* __restrict__ idxb)
{
#pragma clang fp contract(off)
    __shared__ float4 p2s[S];
    const int b = blockIdx.y;
    for (int s = threadIdx.x; s < S; s += 256) {
        float x = pos2[(b * 3 + 0) * S + s];
        float y = pos2[(b * 3 + 1) * S + s];
        float z = pos2[(b * 3 + 2) * S + s];
        float t2 = x * x + y * y + z * z;   // matches np sum order
        p2s[s] = make_float4(x, y, z, t2);
    }
    __syncthreads();

    const int qi = blockIdx.x * 64 + (threadIdx.x >> 2);
    const int sp = threadIdx.x & 3;
    const float x1 = pos1[(b * 3 + 0) * N + qi];
    const float y1 = pos1[(b * 3 + 1) * N + qi];
    const float z1 = pos1[(b * 3 + 2) * N + qi];
    const float t1 = x1 * x1 + y1 * y1 + z1 * z1;

    float d0 = 3.4e38f, d1 = 3.4e38f, d2 = 3.4e38f;
    int i0 = 0x7fffffff, i1 = 0x7fffffff, i2 = 0x7fffffff;

    // each of 4 lanes scans residue class s == sp (mod 4)
    for (int t = 0; t < S / 4; ++t) {
        int s = 4 * t + sp;
        float4 p = p2s[s];
        float dot = x1 * p.x + y1 * p.y + z1 * p.z;
        float dd = (t1 - 2.0f * dot) + p.w;   // reference op order
        if (dd < d2) {
            if (dd < d0)      { d2 = d1; i2 = i1; d1 = d0; i1 = i0; d0 = dd; i0 = s; }
            else if (dd < d1) { d2 = d1; i2 = i1; d1 = dd; i1 = s; }
            else              { d2 = dd; i2 = s; }
        }
    }

    // merge top-3 across the 4 lanes of the query group; (d, idx) lexicographic
    #pragma unroll
    for (int m = 1; m <= 2; m <<= 1) {
        float c0 = __shfl_xor(d0, m), c1 = __shfl_xor(d1, m), c2 = __shfl_xor(d2, m);
        int   j0 = __shfl_xor(i0, m), j1 = __shfl_xor(i1, m), j2 = __shfl_xor(i2, m);
        float cd[3] = {c0, c1, c2};
        int   cj[3] = {j0, j1, j2};
        #pragma unroll
        for (int k = 0; k < 3; ++k) {
            float d = cd[k]; int id = cj[k];
            bool l0 = (d < d0) || (d == d0 && id < i0);
            bool l1 = (d < d1) || (d == d1 && id < i1);
            bool l2 = (d < d2) || (d == d2 && id < i2);
            if (l0)      { d2 = d1; i2 = i1; d1 = d0; i1 = i0; d0 = d; i0 = id; }
            else if (l1) { d2 = d1; i2 = i1; d1 = d; i1 = id; }
            else if (l2) { d2 = d; i2 = id; }
        }
    }

    if (sp == 0) {
        float w0 = 1.f / fmaxf(d0, 1e-10f);
        float w1 = 1.f / fmaxf(d1, 1e-10f);
        float w2 = 1.f / fmaxf(d2, 1e-10f);
        float inv = 1.f / (w0 + w1 + w2);
        // defensive clamp: any numeric surprise becomes a wrong value, not a fault
        i0 = ((unsigned)i0 < S) ? i0 : 0;
        i1 = ((unsigned)i1 < S) ? i1 : 0;
        i2 = ((unsigned)i2 < S) ? i2 : 0;
        int base = (b * N + qi) * 3;
        wgt[base + 0] = w0 * inv; wgt[base + 1] = w1 * inv; wgt[base + 2] = w2 * inv;
        idxb[base + 0] = i0; idxb[base + 1] = i1; idxb[base + 2] = i2;
    }
}

// --------------------------------------------------------- transpose -----
// in: per-batch fp32 [C, L] row-major -> out per-batch bf16 [L, out_stride] at col_off
__global__ void transpose_k(const float* __restrict__ in,
                            __hip_bfloat16* __restrict__ out,
                            int L, int in_bstride, int out_stride, int out_bstride,
                            int col_off)
{
    __shared__ __hip_bfloat16 t[32][33];
    const int b = blockIdx.z;
    const int l0 = blockIdx.x * 32, c0 = blockIdx.y * 32;
    const int tx = threadIdx.x, ty = threadIdx.y;
    const float* ip = in + (size_t)b * in_bstride;
    #pragma unroll
    for (int i = 0; i < 4; ++i)
        t[ty + 8 * i][tx] = __float2bfloat16(ip[(size_t)(c0 + ty + 8 * i) * L + l0 + tx]);
    __syncthreads();
    __hip_bfloat16* op = out + (size_t)b * out_bstride + col_off;
    #pragma unroll
    for (int i = 0; i < 4; ++i)
        op[(size_t)(l0 + ty + 8 * i) * out_stride + c0 + tx] = t[tx][ty + 8 * i];
}

// ------------------------------------------------------------- interp ----
__global__ __launch_bounds__(256) void interp_kernel(
    const __hip_bfloat16* __restrict__ f2T, const float* __restrict__ wgt,
    const int* __restrict__ idxb, __hip_bfloat16* __restrict__ featT)
{
    const int b = blockIdx.y;
    const int d = threadIdx.x;
    const int n0 = blockIdx.x * 8;
    for (int i = 0; i < 8; ++i) {
        int n = n0 + i;
        int base = (b * N + n) * 3;
        int s0 = idxb[base], s1 = idxb[base + 1], s2 = idxb[base + 2];
        s0 = ((unsigned)s0 < S) ? s0 : 0;   // defensive
        s1 = ((unsigned)s1 < S) ? s1 : 0;
        s2 = ((unsigned)s2 < S) ? s2 : 0;
        float w0 = wgt[base], w1 = wgt[base + 1], w2 = wgt[base + 2];
        float v = w0 * bf2f(f2T[((size_t)b * S + s0) * 256 + d])
                + w1 * bf2f(f2T[((size_t)b * S + s1) * 256 + d])
                + w2 * bf2f(f2T[((size_t)b * S + s2) * 256 + d]);
        featT[((size_t)b * N + n) * LD + d] = __float2bfloat16(v);
    }
}

// --------------------------------------------------------------- GEMM ----
// Y[b,n,o] = sum_k W[o,k] * X[b,n,k] + bias[o]
// X rows have stride LD; output written bf16 IN-PLACE over cols 0..256 of the
// same buffer (safe: all 4 lanes reading row n and the lane writing row n are
// in the same wave; reads complete before epilogue writes).
template <int K>
__global__ __launch_bounds__(256) void gemm_kernel(
    const __hip_bfloat16* __restrict__ W, const float* __restrict__ bias,
    __hip_bfloat16* __restrict__ X)
{
    const int w = threadIdx.x >> 6, lane = threadIdx.x & 63;
    const int q = lane >> 4, r = lane & 15;
    const int b = blockIdx.y;
    const int n = blockIdx.x * 64 + w * 16 + r;

    const short* Xr = (const short*)X + ((size_t)b * N + n) * LD + q * 8;
    const short* Wp = (const short*)W + q * 8;

    v4f acc[16];
    #pragma unroll
    for (int mt = 0; mt < 16; ++mt) acc[mt] = (v4f){0.f, 0.f, 0.f, 0.f};

    for (int kk = 0; kk < K / 32; ++kk) {
        short8 bfrag = *(const short8*)(Xr + kk * 32);
        #pragma unroll
        for (int mt = 0; mt < 16; ++mt) {
            short8 afrag = *(const short8*)(Wp + (size_t)(mt * 16 + r) * K + kk * 32);
            acc[mt] = __builtin_amdgcn_mfma_f32_16x16x32_bf16(afrag, bfrag, acc[mt], 0, 0, 0);
        }
    }

    __hip_bfloat16* Yr = X + ((size_t)b * N + n) * LD;
    #pragma unroll
    for (int mt = 0; mt < 16; ++mt) {
        int o = mt * 16 + q * 4;   // C/D layout: row = (lane>>4)*4 + reg
        union { ushort4 u; __hip_bfloat16 h[4]; } pk;
        pk.h[0] = __float2bfloat16(acc[mt][0] + bias[o + 0]);
        pk.h[1] = __float2bfloat16(acc[mt][1] + bias[o + 1]);
        pk.h[2] = __float2bfloat16(acc[mt][2] + bias[o + 2]);
        pk.h[3] = __float2bfloat16(acc[mt][3] + bias[o + 3]);
        *(ushort4*)(Yr + o) = pk.u;
    }
}

// ----------------------------------------------------------- BN stats ----
__global__ __launch_bounds__(256) void stats_kernel(const __hip_bfloat16* __restrict__ Y,
                                                    float* __restrict__ sums)
{
    const int o = threadIdx.x;
    const size_t r0 = (size_t)blockIdx.x * 128;
    float s = 0.f, s2 = 0.f;
    for (int i = 0; i < 128; ++i) {
        float v = bf2f(Y[(r0 + i) * LD + o]);
        s += v; s2 += v * v;
    }
    atomicAdd(&sums[o], s);
    atomicAdd(&sums[256 + o], s2);
}

__global__ void finalize_kernel(const float* __restrict__ sums,
                                const float* __restrict__ g,
                                const float* __restrict__ beta,
                                float* __restrict__ ss)
{
    const int o = threadIdx.x;
    float mean = sums[o] * (1.f / 32768.f);
    float var = sums[256 + o] * (1.f / 32768.f) - mean * mean;
    float rstd = rsqrtf(var + 1e-5f);
    float sc = g[o] * rstd;
    ss[o] = sc;
    ss[256 + o] = beta[o] - mean * sc;
}

// ----------------------------------- normalize+ReLU, in-place on Y -------
__global__ __launch_bounds__(256) void normrelu_kernel(__hip_bfloat16* __restrict__ Y,
                                                       const float* __restrict__ ss)
{
    const int gid = blockIdx.x * 256 + threadIdx.x;   // B*N*64 threads
    const size_t row = gid >> 6;
    const int c = (gid & 63) * 4;
    __hip_bfloat16* p = Y + row * LD + c;
    union { ushort4 u; __hip_bfloat16 h[4]; } v;
    v.u = *(const ushort4*)p;
    #pragma unroll
    for (int j = 0; j < 4; ++j)
        v.h[j] = __float2bfloat16(fmaxf(bf2f(v.h[j]) * ss[c + j] + ss[256 + c + j], 0.f));
    *(ushort4*)p = v.u;
}

// ------------------ final BN+ReLU + transpose to [B,256,N] fp32 out ------
__global__ void final_kernel(const __hip_bfloat16* __restrict__ Y,
                             const float* __restrict__ ss,
                             float* __restrict__ out)
{
    __shared__ float t[32][33];
    const int b = blockIdx.z;
    const int n0 = blockIdx.x * 32, o0 = blockIdx.y * 32;
    const int tx = threadIdx.x, ty = threadIdx.y;
    const float sc = ss[o0 + tx], sh = ss[256 + o0 + tx];
    #pragma unroll
    for (int i = 0; i < 4; ++i) {
        float v = bf2f(Y[((size_t)b * N + n0 + ty + 8 * i) * LD + o0 + tx]);
        t[ty + 8 * i][tx] = fmaxf(v * sc + sh, 0.f);
    }
    __syncthreads();
    #pragma unroll
    for (int i = 0; i < 4; ++i)
        out[((size_t)b * 256 + o0 + ty + 8 * i) * N + n0 + tx] = t[tx][ty + 8 * i];
}

// ------------------------------------------------------------ launch -----
extern "C" void kernel_launch(void* const* d_in, const int* in_sizes, int n_in,
                              void* d_out, int out_size, void* d_ws, size_t ws_size,
                              hipStream_t stream)
{
    (void)in_sizes; (void)n_in; (void)out_size;
    // Workspace layout (total 30 MB):
    //   [0, 384K)        idxb  int[B*N*3]
    //   [384K, 768K)     wgt   float[B*N*3]
    //   [768K, +8K)      sums1/sums2/ss1/ss2 (4 x 512 floats)
    //   [800K, +192K)    W1c   bf16[256*384]
    //   [992K, +128K)    W2c   bf16[256*256]
    //   [2M, 6M)         f2T   bf16[B,S,256]
    //   [6M, 30M)        featT bf16[B,N,LD=384]  (y1/y2 written in-place)
    if (ws_size < (30u << 20)) return;   // clean failure instead of mem-fault

    const float* pos1 = (const float*)d_in[0];
    const float* pos2 = (const float*)d_in[1];
    const float* f1   = (const float*)d_in[2];
    const float* f2   = (const float*)d_in[3];
    const float* W1   = (const float*)d_in[4];
    const float* b1   = (const float*)d_in[5];
    const float* g1   = (const float*)d_in[6];
    const float* be1  = (const float*)d_in[7];
    const float* W2   = (const float*)d_in[8];
    const float* b2   = (const float*)d_in[9];
    const float* g2   = (const float*)d_in[10];
    const float* be2  = (const float*)d_in[11];

    char* ws = (char*)d_ws;
    int*   idxb  = (int*)(ws + 0);
    float* wgt   = (float*)(ws + 393216);
    float* sums1 = (float*)(ws + 786432);
    float* sums2 = sums1 + 512;
    float* ss1   = sums2 + 512;
    float* ss2   = ss1 + 512;
    __hip_bfloat16* W1c   = (__hip_bfloat16*)(ws + 819200);
    __hip_bfloat16* W2c   = (__hip_bfloat16*)(ws + 1015808);
    __hip_bfloat16* f2T   = (__hip_bfloat16*)(ws + (2u << 20));
    __hip_bfloat16* featT = (__hip_bfloat16*)(ws + (6u << 20));

    zero_k<<<4, 256, 0, stream>>>(sums1);   // zeroes sums1+sums2

    cast_w<<<384, 256, 0, stream>>>(W1, W1c, 256 * 384);
    cast_w<<<256, 256, 0, stream>>>(W2, W2c, 256 * 256);

    knn_kernel<<<dim3(N / 64, B), 256, 0, stream>>>(pos1, pos2, wgt, idxb);

    // feature2 [B,256,S] -> f2T [B,S,256]
    transpose_k<<<dim3(S / 32, 256 / 32, B), dim3(32, 8), 0, stream>>>(
        f2, f2T, S, 256 * S, 256, S * 256, 0);
    // feature1 [B,128,N] -> featT[:, :, 256:384]
    transpose_k<<<dim3(N / 32, 128 / 32, B), dim3(32, 8), 0, stream>>>(
        f1, featT, N, 128 * N, LD, N * LD, 256);

    interp_kernel<<<dim3(N / 8, B), 256, 0, stream>>>(f2T, wgt, idxb, featT);

    gemm_kernel<384><<<dim3(N / 64, B), 256, 0, stream>>>(W1c, b1, featT);
    stats_kernel<<<256, 256, 0, stream>>>(featT, sums1);
    finalize_kernel<<<1, 256, 0, stream>>>(sums1, g1, be1, ss1);
    normrelu_kernel<<<B * N / 4, 256, 0, stream>>>(featT, ss1);

    gemm_kernel<256><<<dim3(N / 64, B), 256, 0, stream>>>(W2c, b2, featT);
    stats_kernel<<<256, 256, 0, stream>>>(featT, sums2);
    finalize_kernel<<<1, 256, 0, stream>>>(sums2, g2, be2, ss2);
    final_kernel<<<dim3(N / 32, 256 / 32, B), dim3(32, 8), 0, stream>>>(
        featT, ss2, (float*)d_out);
}